// Round 11
// baseline (142.952 us; speedup 1.0000x reference)
//
#include <hip/hip_runtime.h>
#include <hip/hip_bf16.h>

// GRU-D cell: B=16384, I=128, D=16 -- operand-swapped MFMA, i-INNER loop.
// R3..R10 all plateaued at ~2.2 TB/s: every version read h/gamma/out in
// isolated 64-B windows at 8-KB stride (one i per wave for its whole life)
// -> DRAM page-locality collapse. R11 keeps R9's lane-local MFMA compute
// but iterates i INNER: wave holds one 16-row b-tile and walks 8 consecutive
// i's => 512 B contiguous per row per wave, 2 KB per block, and the 4
// i-range blocks of a b-tile share an XCD (1024%8==0) => full 8-KB rows
// consumed densely per XCD. U is prefetched 1 iteration ahead (L2-resident);
// W/V/b are decoupled from the MFMA C operand (added post-matmul) so their
// loads hide under the MFMA chain. X/M: 8 iterations hit one 64-B line.

typedef float  f32x4_t  __attribute__((ext_vector_type(4)));
typedef short  bf16x8_t __attribute__((ext_vector_type(8)));

constexpr int I_TOT = 128;
constexpr int ROWL  = 2048;   // floats per batch row (I*D)

__device__ __forceinline__ unsigned short bf16_rne(float x) {
    union { float f; unsigned u; } c; c.f = x;
    unsigned u = c.u + 0x7fffu + ((c.u >> 16) & 1u);
    return (unsigned short)(u >> 16);
}
__device__ __forceinline__ float bf16_to_f(unsigned short b) {
    union { float f; unsigned u; } c; c.u = ((unsigned)b) << 16;
    return c.f;
}
__device__ __forceinline__ float fast_sigmoid(float x) {
    float e = __expf(-x);
    return __builtin_amdgcn_rcpf(1.0f + e);
}
__device__ __forceinline__ float fast_tanh(float x) {
    x = fminf(fmaxf(x, -10.0f), 10.0f);
    float e = __expf(-2.0f * x);
    return (1.0f - e) * __builtin_amdgcn_rcpf(1.0f + e);
}

struct BPair { bf16x8_t hi, lo; };

// U fragment from 4 f32 values: hi = [h0..h3|h0..h3], lo = [l0..l3|0,0,0,0]
__device__ __forceinline__ BPair build_b(float u0, float u1, float u2, float u3) {
    unsigned short h0 = bf16_rne(u0), h1 = bf16_rne(u1),
                   h2 = bf16_rne(u2), h3 = bf16_rne(u3);
    unsigned short l0 = bf16_rne(u0 - bf16_to_f(h0));
    unsigned short l1 = bf16_rne(u1 - bf16_to_f(h1));
    unsigned short l2 = bf16_rne(u2 - bf16_to_f(h2));
    unsigned short l3 = bf16_rne(u3 - bf16_to_f(h3));
    BPair p;
    p.hi[0] = (short)h0; p.hi[1] = (short)h1; p.hi[2] = (short)h2; p.hi[3] = (short)h3;
    p.hi[4] = (short)h0; p.hi[5] = (short)h1; p.hi[6] = (short)h2; p.hi[7] = (short)h3;
    p.lo[0] = (short)l0; p.lo[1] = (short)l1; p.lo[2] = (short)l2; p.lo[3] = (short)l3;
    p.lo[4] = 0; p.lo[5] = 0; p.lo[6] = 0; p.lo[7] = 0;
    return p;
}

// hh fragment: [hi(a0..a3) | lo(a0..a3)]
__device__ __forceinline__ bf16x8_t build_a(float a0, float a1, float a2, float a3) {
    unsigned short h0 = bf16_rne(a0), h1 = bf16_rne(a1),
                   h2 = bf16_rne(a2), h3 = bf16_rne(a3);
    unsigned short l0 = bf16_rne(a0 - bf16_to_f(h0));
    unsigned short l1 = bf16_rne(a1 - bf16_to_f(h1));
    unsigned short l2 = bf16_rne(a2 - bf16_to_f(h2));
    unsigned short l3 = bf16_rne(a3 - bf16_to_f(h3));
    bf16x8_t A;
    A[0] = (short)h0; A[1] = (short)h1; A[2] = (short)h2; A[3] = (short)h3;
    A[4] = (short)l0; A[5] = (short)l1; A[6] = (short)l2; A[7] = (short)l3;
    return A;
}

__device__ __forceinline__ f32x4_t mm(bf16x8_t a, bf16x8_t b, f32x4_t c) {
    return __builtin_amdgcn_mfma_f32_16x16x32_bf16(a, b, c, 0, 0, 0);
}

__global__ __launch_bounds__(256)
__attribute__((amdgpu_waves_per_eu(2, 8)))
void gru_d_mfma(
    const float* __restrict__ h,
    const float* __restrict__ X,
    const float* __restrict__ M,
    const float* __restrict__ gam,
    const float* __restrict__ W_r, const float* __restrict__ W_z, const float* __restrict__ W_h,
    const float* __restrict__ U_r, const float* __restrict__ U_z, const float* __restrict__ U_h,
    const float* __restrict__ V_r, const float* __restrict__ V_z, const float* __restrict__ V_h,
    const float* __restrict__ b_r, const float* __restrict__ b_z, const float* __restrict__ b_h,
    float* __restrict__ out)
{
    const int t  = threadIdx.x;
    const int w  = t >> 6;              // wave in block
    const int l  = t & 63;              // lane
    const int bi = l & 15;              // batch row within tile
    const int dA = (l >> 4) * 4;        // d-slot / out-col base

    const int b0 = blockIdx.x * 16;     // b-tile (fast dim: dense rows per XCD)
    const int i0 = blockIdx.y * 32 + w * 8;   // this wave's first feature

    const size_t rowb = (size_t)(b0 + bi) * ROWL + dA;  // h/gam/out lane base
    const size_t xrow = (size_t)(b0 + bi) * I_TOT;      // X/M lane base

    // ---- prefetch iteration 0: h/gamma/X/M and U scalars for i0 ----
    float4 ph = *reinterpret_cast<const float4*>(h   + rowb + i0 * 16);
    float4 pg = *reinterpret_cast<const float4*>(gam + rowb + i0 * 16);
    float px = X[xrow + i0];
    float pm = M[xrow + i0];
    const float* Urp = U_r + i0 * 256 + bi;
    const float* Uzp = U_z + i0 * 256 + bi;
    const float* Uhp = U_h + i0 * 256 + bi;
    float pur0 = Urp[(dA+0)*16], pur1 = Urp[(dA+1)*16],
          pur2 = Urp[(dA+2)*16], pur3 = Urp[(dA+3)*16];
    float puz0 = Uzp[(dA+0)*16], puz1 = Uzp[(dA+1)*16],
          puz2 = Uzp[(dA+2)*16], puz3 = Uzp[(dA+3)*16];
    float puh0 = Uhp[(dA+0)*16], puh1 = Uhp[(dA+1)*16],
          puh2 = Uhp[(dA+2)*16], puh3 = Uhp[(dA+3)*16];

    #pragma unroll
    for (int it = 0; it < 8; ++it) {
        const int i   = i0 + it;
        const int ipf = i0 + ((it + 1) & 7);   // wraps to i0 on last iter (L1-hot)

        // ---- prefetch next iteration's streams ----
        float4 nh = *reinterpret_cast<const float4*>(h   + rowb + ipf * 16);
        float4 ng = *reinterpret_cast<const float4*>(gam + rowb + ipf * 16);
        float nx = X[xrow + ipf];
        float nm = M[xrow + ipf];
        const float* nUr = U_r + ipf * 256 + bi;
        const float* nUz = U_z + ipf * 256 + bi;
        const float* nUh = U_h + ipf * 256 + bi;
        float nur0 = nUr[(dA+0)*16], nur1 = nUr[(dA+1)*16],
              nur2 = nUr[(dA+2)*16], nur3 = nUr[(dA+3)*16];
        float nuz0 = nUz[(dA+0)*16], nuz1 = nUz[(dA+1)*16],
              nuz2 = nUz[(dA+2)*16], nuz3 = nUz[(dA+3)*16];
        float nuh0 = nUh[(dA+0)*16], nuh1 = nUh[(dA+1)*16],
              nuh2 = nUh[(dA+2)*16], nuh3 = nUh[(dA+3)*16];

        // ---- W/V/b loads for current i (consumed AFTER the mfma chain) ----
        const float4 wr4 = *reinterpret_cast<const float4*>(W_r + i*16 + dA);
        const float4 wz4 = *reinterpret_cast<const float4*>(W_z + i*16 + dA);
        const float4 wh4 = *reinterpret_cast<const float4*>(W_h + i*16 + dA);
        const float4 vr4 = *reinterpret_cast<const float4*>(V_r + i*16 + dA);
        const float4 vz4 = *reinterpret_cast<const float4*>(V_z + i*16 + dA);
        const float4 vh4 = *reinterpret_cast<const float4*>(V_h + i*16 + dA);
        const float4 br4 = *reinterpret_cast<const float4*>(b_r + i*16 + dA);
        const float4 bz4 = *reinterpret_cast<const float4*>(b_z + i*16 + dA);
        const float4 bh4 = *reinterpret_cast<const float4*>(b_h + i*16 + dA);

        // ---- build current U fragments from prefetched scalars ----
        BPair Br = build_b(pur0, pur1, pur2, pur3);
        BPair Bz = build_b(puz0, puz1, puz2, puz3);
        BPair Bh = build_b(puh0, puh1, puh2, puh3);

        // ---- hh = h*gamma: lane owns hh[b=bi][dA..dA+3] ----
        float hh0 = ph.x * pg.x, hh1 = ph.y * pg.y,
              hh2 = ph.z * pg.z, hh3 = ph.w * pg.w;
        bf16x8_t Ahh = build_a(hh0, hh1, hh2, hh3);

        // ---- r and z matmul parts (C starts at 0; gate-init added after) ----
        f32x4_t accR, accZ, accH;
        accR[0] = 0.f; accR[1] = 0.f; accR[2] = 0.f; accR[3] = 0.f;
        accZ[0] = 0.f; accZ[1] = 0.f; accZ[2] = 0.f; accZ[3] = 0.f;
        accR = mm(Br.hi, Ahh, accR); accR = mm(Br.lo, Ahh, accR);
        accZ = mm(Bz.hi, Ahh, accZ); accZ = mm(Bz.lo, Ahh, accZ);

        // ---- rhh lane-local ----
        float rh0 = fast_sigmoid(accR[0] + fmaf(px, wr4.x, fmaf(pm, vr4.x, br4.x))) * hh0;
        float rh1 = fast_sigmoid(accR[1] + fmaf(px, wr4.y, fmaf(pm, vr4.y, br4.y))) * hh1;
        float rh2 = fast_sigmoid(accR[2] + fmaf(px, wr4.z, fmaf(pm, vr4.z, br4.z))) * hh2;
        float rh3 = fast_sigmoid(accR[3] + fmaf(px, wr4.w, fmaf(pm, vr4.w, br4.w))) * hh3;
        bf16x8_t Arh = build_a(rh0, rh1, rh2, rh3);

        // ---- h~ gate ----
        accH[0] = 0.f; accH[1] = 0.f; accH[2] = 0.f; accH[3] = 0.f;
        accH = mm(Bh.hi, Arh, accH); accH = mm(Bh.lo, Arh, accH);

        // ---- out = z*hh + (1-z)*tanh(.), lane-local, one float4 store ----
        float4 o;
        {
            float z0 = fast_sigmoid(accZ[0] + fmaf(px, wz4.x, fmaf(pm, vz4.x, bz4.x)));
            float t0 = fast_tanh(accH[0] + fmaf(px, wh4.x, fmaf(pm, vh4.x, bh4.x)));
            o.x = fmaf(z0, hh0 - t0, t0);
            float z1 = fast_sigmoid(accZ[1] + fmaf(px, wz4.y, fmaf(pm, vz4.y, bz4.y)));
            float t1 = fast_tanh(accH[1] + fmaf(px, wh4.y, fmaf(pm, vh4.y, bh4.y)));
            o.y = fmaf(z1, hh1 - t1, t1);
            float z2 = fast_sigmoid(accZ[2] + fmaf(px, wz4.z, fmaf(pm, vz4.z, bz4.z)));
            float t2 = fast_tanh(accH[2] + fmaf(px, wh4.z, fmaf(pm, vh4.z, bh4.z)));
            o.z = fmaf(z2, hh2 - t2, t2);
            float z3 = fast_sigmoid(accZ[3] + fmaf(px, wz4.w, fmaf(pm, vz4.w, bz4.w)));
            float t3 = fast_tanh(accH[3] + fmaf(px, wh4.w, fmaf(pm, vh4.w, bh4.w)));
            o.w = fmaf(z3, hh3 - t3, t3);
        }
        *reinterpret_cast<float4*>(out + rowb + (size_t)i * 16) = o;

        // ---- rotate prefetch ----
        ph = nh; pg = ng; px = nx; pm = nm;
        pur0 = nur0; pur1 = nur1; pur2 = nur2; pur3 = nur3;
        puz0 = nuz0; puz1 = nuz1; puz2 = nuz2; puz3 = nuz3;
        puh0 = nuh0; puh1 = nuh1; puh2 = nuh2; puh3 = nuh3;
    }
}

extern "C" void kernel_launch(void* const* d_in, const int* in_sizes, int n_in,
                              void* d_out, int out_size, void* d_ws, size_t ws_size,
                              hipStream_t stream) {
    const float* h       = (const float*)d_in[0];
    const float* X       = (const float*)d_in[1];
    const float* M       = (const float*)d_in[2];
    const float* gamma_h = (const float*)d_in[3];
    const float* W_r     = (const float*)d_in[4];
    const float* W_z     = (const float*)d_in[5];
    const float* W_h     = (const float*)d_in[6];
    const float* U_r     = (const float*)d_in[7];
    const float* U_z     = (const float*)d_in[8];
    const float* U_h     = (const float*)d_in[9];
    const float* V_r     = (const float*)d_in[10];
    const float* V_z     = (const float*)d_in[11];
    const float* V_h     = (const float*)d_in[12];
    const float* b_r     = (const float*)d_in[13];
    const float* b_z     = (const float*)d_in[14];
    const float* b_h     = (const float*)d_in[15];
    float* out = (float*)d_out;

    dim3 grid(16384 / 16, I_TOT / 32);   // (1024, 4); same-b-tile blocks share an XCD
    dim3 block(256);
    gru_d_mfma<<<grid, block, 0, stream>>>(h, X, M, gamma_h,
                                           W_r, W_z, W_h,
                                           U_r, U_z, U_h,
                                           V_r, V_z, V_h,
                                           b_r, b_z, b_h,
                                           out);
}

// Round 12
// 137.487 us; speedup vs baseline: 1.0398x; 1.0398x over previous
//
#include <hip/hip_runtime.h>
#include <hip/hip_bf16.h>

// GRU-D cell: B=16384, I=128, D=16 -- operand-swapped MFMA, i-INNER loop.
// R12 = R11 with the GRID ORDER swapped. R11's grid (1024 b-tiles, 4 i-grps)
// made b the fast dispatch dim -> the ~2000 co-resident blocks spanned ALL
// 16K batch rows x a 512-B column window: 64-B granules at 8-KB stride over
// the whole array = DRAM row-activate thrash (the ~2.2 TB/s wall seen since
// R3). R12: grid (4, 1024) with i-group FAST, b-tile SLOW -> resident set =
// ~500 consecutive b-tiles x all 128 i = a contiguous ~65-MB window marching
// through h/gamma/out in address order (memcpy-like device-level access).
// Kernel body identical to R11: lane-local MFMA gates, U prefetched one
// iteration ahead, W/V/b decoupled from the MFMA C operand.

typedef float  f32x4_t  __attribute__((ext_vector_type(4)));
typedef short  bf16x8_t __attribute__((ext_vector_type(8)));

constexpr int I_TOT = 128;
constexpr int ROWL  = 2048;   // floats per batch row (I*D)

__device__ __forceinline__ unsigned short bf16_rne(float x) {
    union { float f; unsigned u; } c; c.f = x;
    unsigned u = c.u + 0x7fffu + ((c.u >> 16) & 1u);
    return (unsigned short)(u >> 16);
}
__device__ __forceinline__ float bf16_to_f(unsigned short b) {
    union { float f; unsigned u; } c; c.u = ((unsigned)b) << 16;
    return c.f;
}
__device__ __forceinline__ float fast_sigmoid(float x) {
    float e = __expf(-x);
    return __builtin_amdgcn_rcpf(1.0f + e);
}
__device__ __forceinline__ float fast_tanh(float x) {
    x = fminf(fmaxf(x, -10.0f), 10.0f);
    float e = __expf(-2.0f * x);
    return (1.0f - e) * __builtin_amdgcn_rcpf(1.0f + e);
}

struct BPair { bf16x8_t hi, lo; };

// U fragment from 4 f32 values: hi = [h0..h3|h0..h3], lo = [l0..l3|0,0,0,0]
__device__ __forceinline__ BPair build_b(float u0, float u1, float u2, float u3) {
    unsigned short h0 = bf16_rne(u0), h1 = bf16_rne(u1),
                   h2 = bf16_rne(u2), h3 = bf16_rne(u3);
    unsigned short l0 = bf16_rne(u0 - bf16_to_f(h0));
    unsigned short l1 = bf16_rne(u1 - bf16_to_f(h1));
    unsigned short l2 = bf16_rne(u2 - bf16_to_f(h2));
    unsigned short l3 = bf16_rne(u3 - bf16_to_f(h3));
    BPair p;
    p.hi[0] = (short)h0; p.hi[1] = (short)h1; p.hi[2] = (short)h2; p.hi[3] = (short)h3;
    p.hi[4] = (short)h0; p.hi[5] = (short)h1; p.hi[6] = (short)h2; p.hi[7] = (short)h3;
    p.lo[0] = (short)l0; p.lo[1] = (short)l1; p.lo[2] = (short)l2; p.lo[3] = (short)l3;
    p.lo[4] = 0; p.lo[5] = 0; p.lo[6] = 0; p.lo[7] = 0;
    return p;
}

// hh fragment: [hi(a0..a3) | lo(a0..a3)]
__device__ __forceinline__ bf16x8_t build_a(float a0, float a1, float a2, float a3) {
    unsigned short h0 = bf16_rne(a0), h1 = bf16_rne(a1),
                   h2 = bf16_rne(a2), h3 = bf16_rne(a3);
    unsigned short l0 = bf16_rne(a0 - bf16_to_f(h0));
    unsigned short l1 = bf16_rne(a1 - bf16_to_f(h1));
    unsigned short l2 = bf16_rne(a2 - bf16_to_f(h2));
    unsigned short l3 = bf16_rne(a3 - bf16_to_f(h3));
    bf16x8_t A;
    A[0] = (short)h0; A[1] = (short)h1; A[2] = (short)h2; A[3] = (short)h3;
    A[4] = (short)l0; A[5] = (short)l1; A[6] = (short)l2; A[7] = (short)l3;
    return A;
}

__device__ __forceinline__ f32x4_t mm(bf16x8_t a, bf16x8_t b, f32x4_t c) {
    return __builtin_amdgcn_mfma_f32_16x16x32_bf16(a, b, c, 0, 0, 0);
}

__global__ __launch_bounds__(256)
__attribute__((amdgpu_waves_per_eu(2, 8)))
void gru_d_mfma(
    const float* __restrict__ h,
    const float* __restrict__ X,
    const float* __restrict__ M,
    const float* __restrict__ gam,
    const float* __restrict__ W_r, const float* __restrict__ W_z, const float* __restrict__ W_h,
    const float* __restrict__ U_r, const float* __restrict__ U_z, const float* __restrict__ U_h,
    const float* __restrict__ V_r, const float* __restrict__ V_z, const float* __restrict__ V_h,
    const float* __restrict__ b_r, const float* __restrict__ b_z, const float* __restrict__ b_h,
    float* __restrict__ out)
{
    const int t  = threadIdx.x;
    const int w  = t >> 6;              // wave in block
    const int l  = t & 63;              // lane
    const int bi = l & 15;              // batch row within tile
    const int dA = (l >> 4) * 4;        // d-slot / out-col base

    const int b0 = blockIdx.y * 16;           // b-tile (SLOW dim: marching slab)
    const int i0 = blockIdx.x * 32 + w * 8;   // this wave's first feature (FAST dim)

    const size_t rowb = (size_t)(b0 + bi) * ROWL + dA;  // h/gam/out lane base
    const size_t xrow = (size_t)(b0 + bi) * I_TOT;      // X/M lane base

    // ---- prefetch iteration 0: h/gamma/X/M and U scalars for i0 ----
    float4 ph = *reinterpret_cast<const float4*>(h   + rowb + i0 * 16);
    float4 pg = *reinterpret_cast<const float4*>(gam + rowb + i0 * 16);
    float px = X[xrow + i0];
    float pm = M[xrow + i0];
    const float* Urp = U_r + i0 * 256 + bi;
    const float* Uzp = U_z + i0 * 256 + bi;
    const float* Uhp = U_h + i0 * 256 + bi;
    float pur0 = Urp[(dA+0)*16], pur1 = Urp[(dA+1)*16],
          pur2 = Urp[(dA+2)*16], pur3 = Urp[(dA+3)*16];
    float puz0 = Uzp[(dA+0)*16], puz1 = Uzp[(dA+1)*16],
          puz2 = Uzp[(dA+2)*16], puz3 = Uzp[(dA+3)*16];
    float puh0 = Uhp[(dA+0)*16], puh1 = Uhp[(dA+1)*16],
          puh2 = Uhp[(dA+2)*16], puh3 = Uhp[(dA+3)*16];

    #pragma unroll
    for (int it = 0; it < 8; ++it) {
        const int i   = i0 + it;
        const int ipf = i0 + ((it + 1) & 7);   // wraps to i0 on last iter (L1-hot)

        // ---- prefetch next iteration's streams ----
        float4 nh = *reinterpret_cast<const float4*>(h   + rowb + ipf * 16);
        float4 ng = *reinterpret_cast<const float4*>(gam + rowb + ipf * 16);
        float nx = X[xrow + ipf];
        float nm = M[xrow + ipf];
        const float* nUr = U_r + ipf * 256 + bi;
        const float* nUz = U_z + ipf * 256 + bi;
        const float* nUh = U_h + ipf * 256 + bi;
        float nur0 = nUr[(dA+0)*16], nur1 = nUr[(dA+1)*16],
              nur2 = nUr[(dA+2)*16], nur3 = nUr[(dA+3)*16];
        float nuz0 = nUz[(dA+0)*16], nuz1 = nUz[(dA+1)*16],
              nuz2 = nUz[(dA+2)*16], nuz3 = nUz[(dA+3)*16];
        float nuh0 = nUh[(dA+0)*16], nuh1 = nUh[(dA+1)*16],
              nuh2 = nUh[(dA+2)*16], nuh3 = nUh[(dA+3)*16];

        // ---- W/V/b loads for current i (consumed AFTER the mfma chain) ----
        const float4 wr4 = *reinterpret_cast<const float4*>(W_r + i*16 + dA);
        const float4 wz4 = *reinterpret_cast<const float4*>(W_z + i*16 + dA);
        const float4 wh4 = *reinterpret_cast<const float4*>(W_h + i*16 + dA);
        const float4 vr4 = *reinterpret_cast<const float4*>(V_r + i*16 + dA);
        const float4 vz4 = *reinterpret_cast<const float4*>(V_z + i*16 + dA);
        const float4 vh4 = *reinterpret_cast<const float4*>(V_h + i*16 + dA);
        const float4 br4 = *reinterpret_cast<const float4*>(b_r + i*16 + dA);
        const float4 bz4 = *reinterpret_cast<const float4*>(b_z + i*16 + dA);
        const float4 bh4 = *reinterpret_cast<const float4*>(b_h + i*16 + dA);

        // ---- build current U fragments from prefetched scalars ----
        BPair Br = build_b(pur0, pur1, pur2, pur3);
        BPair Bz = build_b(puz0, puz1, puz2, puz3);
        BPair Bh = build_b(puh0, puh1, puh2, puh3);

        // ---- hh = h*gamma: lane owns hh[b=bi][dA..dA+3] ----
        float hh0 = ph.x * pg.x, hh1 = ph.y * pg.y,
              hh2 = ph.z * pg.z, hh3 = ph.w * pg.w;
        bf16x8_t Ahh = build_a(hh0, hh1, hh2, hh3);

        // ---- r and z matmul parts (C starts at 0; gate-init added after) ----
        f32x4_t accR, accZ, accH;
        accR[0] = 0.f; accR[1] = 0.f; accR[2] = 0.f; accR[3] = 0.f;
        accZ[0] = 0.f; accZ[1] = 0.f; accZ[2] = 0.f; accZ[3] = 0.f;
        accR = mm(Br.hi, Ahh, accR); accR = mm(Br.lo, Ahh, accR);
        accZ = mm(Bz.hi, Ahh, accZ); accZ = mm(Bz.lo, Ahh, accZ);

        // ---- rhh lane-local ----
        float rh0 = fast_sigmoid(accR[0] + fmaf(px, wr4.x, fmaf(pm, vr4.x, br4.x))) * hh0;
        float rh1 = fast_sigmoid(accR[1] + fmaf(px, wr4.y, fmaf(pm, vr4.y, br4.y))) * hh1;
        float rh2 = fast_sigmoid(accR[2] + fmaf(px, wr4.z, fmaf(pm, vr4.z, br4.z))) * hh2;
        float rh3 = fast_sigmoid(accR[3] + fmaf(px, wr4.w, fmaf(pm, vr4.w, br4.w))) * hh3;
        bf16x8_t Arh = build_a(rh0, rh1, rh2, rh3);

        // ---- h~ gate ----
        accH[0] = 0.f; accH[1] = 0.f; accH[2] = 0.f; accH[3] = 0.f;
        accH = mm(Bh.hi, Arh, accH); accH = mm(Bh.lo, Arh, accH);

        // ---- out = z*hh + (1-z)*tanh(.), lane-local, one float4 store ----
        float4 o;
        {
            float z0 = fast_sigmoid(accZ[0] + fmaf(px, wz4.x, fmaf(pm, vz4.x, bz4.x)));
            float t0 = fast_tanh(accH[0] + fmaf(px, wh4.x, fmaf(pm, vh4.x, bh4.x)));
            o.x = fmaf(z0, hh0 - t0, t0);
            float z1 = fast_sigmoid(accZ[1] + fmaf(px, wz4.y, fmaf(pm, vz4.y, bz4.y)));
            float t1 = fast_tanh(accH[1] + fmaf(px, wh4.y, fmaf(pm, vh4.y, bh4.y)));
            o.y = fmaf(z1, hh1 - t1, t1);
            float z2 = fast_sigmoid(accZ[2] + fmaf(px, wz4.z, fmaf(pm, vz4.z, bz4.z)));
            float t2 = fast_tanh(accH[2] + fmaf(px, wh4.z, fmaf(pm, vh4.z, bh4.z)));
            o.z = fmaf(z2, hh2 - t2, t2);
            float z3 = fast_sigmoid(accZ[3] + fmaf(px, wz4.w, fmaf(pm, vz4.w, bz4.w)));
            float t3 = fast_tanh(accH[3] + fmaf(px, wh4.w, fmaf(pm, vh4.w, bh4.w)));
            o.w = fmaf(z3, hh3 - t3, t3);
        }
        *reinterpret_cast<float4*>(out + rowb + (size_t)i * 16) = o;

        // ---- rotate prefetch ----
        ph = nh; pg = ng; px = nx; pm = nm;
        pur0 = nur0; pur1 = nur1; pur2 = nur2; pur3 = nur3;
        puz0 = nuz0; puz1 = nuz1; puz2 = nuz2; puz3 = nuz3;
        puh0 = nuh0; puh1 = nuh1; puh2 = nuh2; puh3 = nuh3;
    }
}

extern "C" void kernel_launch(void* const* d_in, const int* in_sizes, int n_in,
                              void* d_out, int out_size, void* d_ws, size_t ws_size,
                              hipStream_t stream) {
    const float* h       = (const float*)d_in[0];
    const float* X       = (const float*)d_in[1];
    const float* M       = (const float*)d_in[2];
    const float* gamma_h = (const float*)d_in[3];
    const float* W_r     = (const float*)d_in[4];
    const float* W_z     = (const float*)d_in[5];
    const float* W_h     = (const float*)d_in[6];
    const float* U_r     = (const float*)d_in[7];
    const float* U_z     = (const float*)d_in[8];
    const float* U_h     = (const float*)d_in[9];
    const float* V_r     = (const float*)d_in[10];
    const float* V_z     = (const float*)d_in[11];
    const float* V_h     = (const float*)d_in[12];
    const float* b_r     = (const float*)d_in[13];
    const float* b_z     = (const float*)d_in[14];
    const float* b_h     = (const float*)d_in[15];
    float* out = (float*)d_out;

    // i-group FAST (x), b-tile SLOW (y): resident blocks = contiguous b-slab
    // covering all 128 i -> device-wide address-ordered marching window.
    dim3 grid(I_TOT / 32, 16384 / 16);   // (4, 1024)
    dim3 block(256);
    gru_d_mfma<<<grid, block, 0, stream>>>(h, X, M, gamma_h,
                                           W_r, W_z, W_h,
                                           U_r, U_z, U_h,
                                           V_r, V_z, V_h,
                                           b_r, b_z, b_h,
                                           out);
}

// Round 13
// 119.301 us; speedup vs baseline: 1.1982x; 1.1524x over previous
//
#include <hip/hip_runtime.h>
#include <hip/hip_bf16.h>

// GRU-D cell: B=16384, I=128, D=16 -- staged-stream + lane-local MFMA.
// R3..R12 all issued vector loads whose 64 lanes touch 16 scattered 64-B
// segments (16 rows x 8-KB stride) -- never a contiguous wave-load. R13
// splits the kernel: Phase 1 streams h/gamma with CONTIGUOUS 1-KB wave
// instructions (the m13 6.3-TB/s shape), computes hh, stages it in LDS
// (16 rows x 512 cols, stride 516 words). Phase 2 = R12's lane-local MFMA
// body with hh from ds_read_b128 (LDS latency ~120cy, hidden by 4 waves/SIMD
// + prefetch) instead of scattered global. Stores stay direct: the same wave
// writes i and i+1 back-to-back -> L2 merges into full lines.
// LDS 33 KB/block -> 4 blocks/CU -> 4 waves/SIMD.

typedef float  f32x4_t  __attribute__((ext_vector_type(4)));
typedef short  bf16x8_t __attribute__((ext_vector_type(8)));

constexpr int I_TOT = 128;
constexpr int ROWL  = 2048;   // floats per batch row (I*D)
constexpr int SW    = 516;    // LDS row stride in words (pad 4: 2-way banks, 16B-aligned)

__device__ __forceinline__ unsigned short bf16_rne(float x) {
    union { float f; unsigned u; } c; c.f = x;
    unsigned u = c.u + 0x7fffu + ((c.u >> 16) & 1u);
    return (unsigned short)(u >> 16);
}
__device__ __forceinline__ float bf16_to_f(unsigned short b) {
    union { float f; unsigned u; } c; c.u = ((unsigned)b) << 16;
    return c.f;
}
__device__ __forceinline__ float fast_sigmoid(float x) {
    float e = __expf(-x);
    return __builtin_amdgcn_rcpf(1.0f + e);
}
__device__ __forceinline__ float fast_tanh(float x) {
    x = fminf(fmaxf(x, -10.0f), 10.0f);
    float e = __expf(-2.0f * x);
    return (1.0f - e) * __builtin_amdgcn_rcpf(1.0f + e);
}

struct BPair { bf16x8_t hi, lo; };

__device__ __forceinline__ BPair build_b(float u0, float u1, float u2, float u3) {
    unsigned short h0 = bf16_rne(u0), h1 = bf16_rne(u1),
                   h2 = bf16_rne(u2), h3 = bf16_rne(u3);
    unsigned short l0 = bf16_rne(u0 - bf16_to_f(h0));
    unsigned short l1 = bf16_rne(u1 - bf16_to_f(h1));
    unsigned short l2 = bf16_rne(u2 - bf16_to_f(h2));
    unsigned short l3 = bf16_rne(u3 - bf16_to_f(h3));
    BPair p;
    p.hi[0] = (short)h0; p.hi[1] = (short)h1; p.hi[2] = (short)h2; p.hi[3] = (short)h3;
    p.hi[4] = (short)h0; p.hi[5] = (short)h1; p.hi[6] = (short)h2; p.hi[7] = (short)h3;
    p.lo[0] = (short)l0; p.lo[1] = (short)l1; p.lo[2] = (short)l2; p.lo[3] = (short)l3;
    p.lo[4] = 0; p.lo[5] = 0; p.lo[6] = 0; p.lo[7] = 0;
    return p;
}

__device__ __forceinline__ bf16x8_t build_a(float a0, float a1, float a2, float a3) {
    unsigned short h0 = bf16_rne(a0), h1 = bf16_rne(a1),
                   h2 = bf16_rne(a2), h3 = bf16_rne(a3);
    unsigned short l0 = bf16_rne(a0 - bf16_to_f(h0));
    unsigned short l1 = bf16_rne(a1 - bf16_to_f(h1));
    unsigned short l2 = bf16_rne(a2 - bf16_to_f(h2));
    unsigned short l3 = bf16_rne(a3 - bf16_to_f(h3));
    bf16x8_t A;
    A[0] = (short)h0; A[1] = (short)h1; A[2] = (short)h2; A[3] = (short)h3;
    A[4] = (short)l0; A[5] = (short)l1; A[6] = (short)l2; A[7] = (short)l3;
    return A;
}

__device__ __forceinline__ f32x4_t mm(bf16x8_t a, bf16x8_t b, f32x4_t c) {
    return __builtin_amdgcn_mfma_f32_16x16x32_bf16(a, b, c, 0, 0, 0);
}

__global__ __launch_bounds__(256)
__attribute__((amdgpu_waves_per_eu(3, 8)))
void gru_d_mfma(
    const float* __restrict__ h,
    const float* __restrict__ X,
    const float* __restrict__ M,
    const float* __restrict__ gam,
    const float* __restrict__ W_r, const float* __restrict__ W_z, const float* __restrict__ W_h,
    const float* __restrict__ U_r, const float* __restrict__ U_z, const float* __restrict__ U_h,
    const float* __restrict__ V_r, const float* __restrict__ V_z, const float* __restrict__ V_h,
    const float* __restrict__ b_r, const float* __restrict__ b_z, const float* __restrict__ b_h,
    float* __restrict__ out)
{
    __shared__ __align__(16) float shh[16 * SW];

    const int t  = threadIdx.x;
    const int w  = t >> 6;              // wave in block
    const int l  = t & 63;              // lane
    const int bi = l & 15;              // batch row within tile (phase 2)
    const int dA = (l >> 4) * 4;        // d-slot / out-col base (phase 2)

    const int b0 = blockIdx.y * 16;     // b-tile
    const int i0 = blockIdx.x * 32;     // block's first feature

    // ================= Phase 1: contiguous stream -> hh in LDS ===========
    // Wave w stages rows 4w..4w+3. Per row: two contiguous 1-KB wave loads
    // of h and gamma (full 128-B lines), product, dense ds_write_b128.
    {
        const int r0 = 4 * w;
#define STAGE(rr)                                                             \
        {                                                                     \
            const size_t gb = (size_t)(b0 + r0 + (rr)) * ROWL + i0 * 16;      \
            float4 h0 = *reinterpret_cast<const float4*>(h   + gb + 4 * l);   \
            float4 h1 = *reinterpret_cast<const float4*>(h   + gb + 256 + 4 * l); \
            float4 g0 = *reinterpret_cast<const float4*>(gam + gb + 4 * l);   \
            float4 g1 = *reinterpret_cast<const float4*>(gam + gb + 256 + 4 * l); \
            float4 p0, p1;                                                    \
            p0.x = h0.x * g0.x; p0.y = h0.y * g0.y;                           \
            p0.z = h0.z * g0.z; p0.w = h0.w * g0.w;                           \
            p1.x = h1.x * g1.x; p1.y = h1.y * g1.y;                           \
            p1.z = h1.z * g1.z; p1.w = h1.w * g1.w;                           \
            *reinterpret_cast<float4*>(&shh[(r0 + (rr)) * SW + 4 * l]) = p0;  \
            *reinterpret_cast<float4*>(&shh[(r0 + (rr)) * SW + 256 + 4 * l]) = p1; \
        }
        STAGE(0) STAGE(1) STAGE(2) STAGE(3)
#undef STAGE
    }
    __syncthreads();

    // ================= Phase 2: lane-local MFMA over 8 i's ===============
    const int iw0 = i0 + w * 8;                         // this wave's first i
    const size_t orow = (size_t)(b0 + bi) * ROWL + dA;  // out lane base
    const size_t xrow = (size_t)(b0 + bi) * I_TOT;      // X/M lane base

    // prefetch iteration 0
    float4 phh = *reinterpret_cast<const float4*>(&shh[bi * SW + (w * 8) * 16 + dA]);
    float px = X[xrow + iw0];
    float pm = M[xrow + iw0];
    const float* Urp = U_r + iw0 * 256 + bi;
    const float* Uzp = U_z + iw0 * 256 + bi;
    const float* Uhp = U_h + iw0 * 256 + bi;
    float pur0 = Urp[(dA+0)*16], pur1 = Urp[(dA+1)*16],
          pur2 = Urp[(dA+2)*16], pur3 = Urp[(dA+3)*16];
    float puz0 = Uzp[(dA+0)*16], puz1 = Uzp[(dA+1)*16],
          puz2 = Uzp[(dA+2)*16], puz3 = Uzp[(dA+3)*16];
    float puh0 = Uhp[(dA+0)*16], puh1 = Uhp[(dA+1)*16],
          puh2 = Uhp[(dA+2)*16], puh3 = Uhp[(dA+3)*16];

    #pragma unroll
    for (int it = 0; it < 8; ++it) {
        const int i    = iw0 + it;
        const int itpf = (it + 1) & 7;       // wraps (L1/LDS-hot re-read)
        const int ipf  = iw0 + itpf;

        // ---- prefetch next iteration ----
        float4 nhh = *reinterpret_cast<const float4*>(
            &shh[bi * SW + (w * 8 + itpf) * 16 + dA]);
        float nx = X[xrow + ipf];
        float nm = M[xrow + ipf];
        const float* nUr = U_r + ipf * 256 + bi;
        const float* nUz = U_z + ipf * 256 + bi;
        const float* nUh = U_h + ipf * 256 + bi;
        float nur0 = nUr[(dA+0)*16], nur1 = nUr[(dA+1)*16],
              nur2 = nUr[(dA+2)*16], nur3 = nUr[(dA+3)*16];
        float nuz0 = nUz[(dA+0)*16], nuz1 = nUz[(dA+1)*16],
              nuz2 = nUz[(dA+2)*16], nuz3 = nUz[(dA+3)*16];
        float nuh0 = nUh[(dA+0)*16], nuh1 = nUh[(dA+1)*16],
              nuh2 = nUh[(dA+2)*16], nuh3 = nUh[(dA+3)*16];

        // ---- W/V/b for current i (consumed after the mfma chain) ----
        const float4 wr4 = *reinterpret_cast<const float4*>(W_r + i*16 + dA);
        const float4 wz4 = *reinterpret_cast<const float4*>(W_z + i*16 + dA);
        const float4 wh4 = *reinterpret_cast<const float4*>(W_h + i*16 + dA);
        const float4 vr4 = *reinterpret_cast<const float4*>(V_r + i*16 + dA);
        const float4 vz4 = *reinterpret_cast<const float4*>(V_z + i*16 + dA);
        const float4 vh4 = *reinterpret_cast<const float4*>(V_h + i*16 + dA);
        const float4 br4 = *reinterpret_cast<const float4*>(b_r + i*16 + dA);
        const float4 bz4 = *reinterpret_cast<const float4*>(b_z + i*16 + dA);
        const float4 bh4 = *reinterpret_cast<const float4*>(b_h + i*16 + dA);

        // ---- current U fragments from prefetched scalars ----
        BPair Br = build_b(pur0, pur1, pur2, pur3);
        BPair Bz = build_b(puz0, puz1, puz2, puz3);
        BPair Bh = build_b(puh0, puh1, puh2, puh3);

        // ---- hh (already h*gamma, staged): lane owns hh[bi][dA..dA+3] ----
        float hh0 = phh.x, hh1 = phh.y, hh2 = phh.z, hh3 = phh.w;
        bf16x8_t Ahh = build_a(hh0, hh1, hh2, hh3);

        // ---- r and z matmul parts ----
        f32x4_t accR, accZ, accH;
        accR[0] = 0.f; accR[1] = 0.f; accR[2] = 0.f; accR[3] = 0.f;
        accZ[0] = 0.f; accZ[1] = 0.f; accZ[2] = 0.f; accZ[3] = 0.f;
        accR = mm(Br.hi, Ahh, accR); accR = mm(Br.lo, Ahh, accR);
        accZ = mm(Bz.hi, Ahh, accZ); accZ = mm(Bz.lo, Ahh, accZ);

        // ---- rhh lane-local ----
        float rh0 = fast_sigmoid(accR[0] + fmaf(px, wr4.x, fmaf(pm, vr4.x, br4.x))) * hh0;
        float rh1 = fast_sigmoid(accR[1] + fmaf(px, wr4.y, fmaf(pm, vr4.y, br4.y))) * hh1;
        float rh2 = fast_sigmoid(accR[2] + fmaf(px, wr4.z, fmaf(pm, vr4.z, br4.z))) * hh2;
        float rh3 = fast_sigmoid(accR[3] + fmaf(px, wr4.w, fmaf(pm, vr4.w, br4.w))) * hh3;
        bf16x8_t Arh = build_a(rh0, rh1, rh2, rh3);

        // ---- h~ gate ----
        accH[0] = 0.f; accH[1] = 0.f; accH[2] = 0.f; accH[3] = 0.f;
        accH = mm(Bh.hi, Arh, accH); accH = mm(Bh.lo, Arh, accH);

        // ---- out = z*hh + (1-z)*tanh(.), lane-local float4 store ----
        float4 o;
        {
            float z0 = fast_sigmoid(accZ[0] + fmaf(px, wz4.x, fmaf(pm, vz4.x, bz4.x)));
            float t0 = fast_tanh(accH[0] + fmaf(px, wh4.x, fmaf(pm, vh4.x, bh4.x)));
            o.x = fmaf(z0, hh0 - t0, t0);
            float z1 = fast_sigmoid(accZ[1] + fmaf(px, wz4.y, fmaf(pm, vz4.y, bz4.y)));
            float t1 = fast_tanh(accH[1] + fmaf(px, wh4.y, fmaf(pm, vh4.y, bh4.y)));
            o.y = fmaf(z1, hh1 - t1, t1);
            float z2 = fast_sigmoid(accZ[2] + fmaf(px, wz4.z, fmaf(pm, vz4.z, bz4.z)));
            float t2 = fast_tanh(accH[2] + fmaf(px, wh4.z, fmaf(pm, vh4.z, bh4.z)));
            o.z = fmaf(z2, hh2 - t2, t2);
            float z3 = fast_sigmoid(accZ[3] + fmaf(px, wz4.w, fmaf(pm, vz4.w, bz4.w)));
            float t3 = fast_tanh(accH[3] + fmaf(px, wh4.w, fmaf(pm, vh4.w, bh4.w)));
            o.w = fmaf(z3, hh3 - t3, t3);
        }
        *reinterpret_cast<float4*>(out + orow + (size_t)i * 16) = o;

        // ---- rotate prefetch ----
        phh = nhh; px = nx; pm = nm;
        pur0 = nur0; pur1 = nur1; pur2 = nur2; pur3 = nur3;
        puz0 = nuz0; puz1 = nuz1; puz2 = nuz2; puz3 = nuz3;
        puh0 = nuh0; puh1 = nuh1; puh2 = nuh2; puh3 = nuh3;
    }
}

extern "C" void kernel_launch(void* const* d_in, const int* in_sizes, int n_in,
                              void* d_out, int out_size, void* d_ws, size_t ws_size,
                              hipStream_t stream) {
    const float* h       = (const float*)d_in[0];
    const float* X       = (const float*)d_in[1];
    const float* M       = (const float*)d_in[2];
    const float* gamma_h = (const float*)d_in[3];
    const float* W_r     = (const float*)d_in[4];
    const float* W_z     = (const float*)d_in[5];
    const float* W_h     = (const float*)d_in[6];
    const float* U_r     = (const float*)d_in[7];
    const float* U_z     = (const float*)d_in[8];
    const float* U_h     = (const float*)d_in[9];
    const float* V_r     = (const float*)d_in[10];
    const float* V_z     = (const float*)d_in[11];
    const float* V_h     = (const float*)d_in[12];
    const float* b_r     = (const float*)d_in[13];
    const float* b_z     = (const float*)d_in[14];
    const float* b_h     = (const float*)d_in[15];
    float* out = (float*)d_out;

    dim3 grid(I_TOT / 32, 16384 / 16);   // (4, 1024)
    dim3 block(256);
    gru_d_mfma<<<grid, block, 0, stream>>>(h, X, M, gamma_h,
                                           W_r, W_z, W_h,
                                           U_r, U_z, U_h,
                                           V_r, V_z, V_h,
                                           b_r, b_z, b_h,
                                           out);
}

// Round 14
// 114.231 us; speedup vs baseline: 1.2514x; 1.0444x over previous
//
#include <hip/hip_runtime.h>
#include <hip/hip_bf16.h>

// GRU-D cell: B=16384, I=128, D=16 -- staged-stream + lane-local MFMA (R13)
// with the VALU diet (R14):
//  * all f32->bf16 via __float2bfloat16 casts (HW v_cvt_pk_bf16_f32; the old
//    software bf16_rne was ~5 VALU ops/value, ~150 ops/iter)
//  * 3 MFMAs/iter (was 6): compensation lives on the hh side only,
//    A=[hh_hi|hh_lo], B=[U_hi|U_hi] => (hh_hi+hh_lo)*U_hi in one mfma.
//    U_lo dropped: +~1e-2 pre-activation error, predicted absmax 0.02-0.05
//    vs threshold 0.0975.
//  * gate init x*W+m*V+b is the MFMA C-input (no post-add chain)
//  * dead wrap-around prefetch removed (static guard, loop fully unrolled)
// Phase 1 (unchanged): contiguous 1-KB wave loads of h/gamma -> hh staged in
// LDS (16 x 512, stride 516 words: 2-way-bank-free ds_read_b128).

typedef float  f32x4_t  __attribute__((ext_vector_type(4)));
typedef short  bf16x8_t __attribute__((ext_vector_type(8)));

constexpr int I_TOT = 128;
constexpr int ROWL  = 2048;   // floats per batch row (I*D)
constexpr int SW    = 516;    // LDS row stride in words

__device__ __forceinline__ unsigned short bf16c(float x) {
    union { __hip_bfloat16 b; unsigned short u; } cv;
    cv.b = __float2bfloat16(x);
    return cv.u;
}
__device__ __forceinline__ float bf16_to_f(unsigned short b) {
    union { float f; unsigned u; } c; c.u = ((unsigned)b) << 16;
    return c.f;
}
__device__ __forceinline__ float fast_sigmoid(float x) {
    float e = __expf(-x);
    return __builtin_amdgcn_rcpf(1.0f + e);
}
__device__ __forceinline__ float fast_tanh(float x) {
    x = fminf(fmaxf(x, -10.0f), 10.0f);
    float e = __expf(-2.0f * x);
    return (1.0f - e) * __builtin_amdgcn_rcpf(1.0f + e);
}

// compensated A fragment: [hi(a0..a3) | lo(a0..a3)]
__device__ __forceinline__ bf16x8_t build_a(float a0, float a1, float a2, float a3) {
    unsigned short h0 = bf16c(a0), h1 = bf16c(a1),
                   h2 = bf16c(a2), h3 = bf16c(a3);
    unsigned short l0 = bf16c(a0 - bf16_to_f(h0));
    unsigned short l1 = bf16c(a1 - bf16_to_f(h1));
    unsigned short l2 = bf16c(a2 - bf16_to_f(h2));
    unsigned short l3 = bf16c(a3 - bf16_to_f(h3));
    bf16x8_t A;
    A[0] = (short)h0; A[1] = (short)h1; A[2] = (short)h2; A[3] = (short)h3;
    A[4] = (short)l0; A[5] = (short)l1; A[6] = (short)l2; A[7] = (short)l3;
    return A;
}

// U fragment, hi only, duplicated across both K halves
__device__ __forceinline__ bf16x8_t build_u(float u0, float u1, float u2, float u3) {
    unsigned short h0 = bf16c(u0), h1 = bf16c(u1),
                   h2 = bf16c(u2), h3 = bf16c(u3);
    bf16x8_t B;
    B[0] = (short)h0; B[1] = (short)h1; B[2] = (short)h2; B[3] = (short)h3;
    B[4] = (short)h0; B[5] = (short)h1; B[6] = (short)h2; B[7] = (short)h3;
    return B;
}

__device__ __forceinline__ f32x4_t mm(bf16x8_t a, bf16x8_t b, f32x4_t c) {
    return __builtin_amdgcn_mfma_f32_16x16x32_bf16(a, b, c, 0, 0, 0);
}

__global__ __launch_bounds__(256)
__attribute__((amdgpu_waves_per_eu(3, 8)))
void gru_d_mfma(
    const float* __restrict__ h,
    const float* __restrict__ X,
    const float* __restrict__ M,
    const float* __restrict__ gam,
    const float* __restrict__ W_r, const float* __restrict__ W_z, const float* __restrict__ W_h,
    const float* __restrict__ U_r, const float* __restrict__ U_z, const float* __restrict__ U_h,
    const float* __restrict__ V_r, const float* __restrict__ V_z, const float* __restrict__ V_h,
    const float* __restrict__ b_r, const float* __restrict__ b_z, const float* __restrict__ b_h,
    float* __restrict__ out)
{
    __shared__ __align__(16) float shh[16 * SW];

    const int t  = threadIdx.x;
    const int w  = t >> 6;              // wave in block
    const int l  = t & 63;              // lane
    const int bi = l & 15;              // batch row within tile (phase 2)
    const int dA = (l >> 4) * 4;        // d-slot / out-col base (phase 2)

    const int b0 = blockIdx.y * 16;     // b-tile
    const int i0 = blockIdx.x * 32;     // block's first feature

    // ======== Phase 1: contiguous stream -> hh in LDS (unchanged) ========
    {
        const int r0 = 4 * w;
#define STAGE(rr)                                                             \
        {                                                                     \
            const size_t gb = (size_t)(b0 + r0 + (rr)) * ROWL + i0 * 16;      \
            float4 h0 = *reinterpret_cast<const float4*>(h   + gb + 4 * l);   \
            float4 h1 = *reinterpret_cast<const float4*>(h   + gb + 256 + 4 * l); \
            float4 g0 = *reinterpret_cast<const float4*>(gam + gb + 4 * l);   \
            float4 g1 = *reinterpret_cast<const float4*>(gam + gb + 256 + 4 * l); \
            float4 p0, p1;                                                    \
            p0.x = h0.x * g0.x; p0.y = h0.y * g0.y;                           \
            p0.z = h0.z * g0.z; p0.w = h0.w * g0.w;                           \
            p1.x = h1.x * g1.x; p1.y = h1.y * g1.y;                           \
            p1.z = h1.z * g1.z; p1.w = h1.w * g1.w;                           \
            *reinterpret_cast<float4*>(&shh[(r0 + (rr)) * SW + 4 * l]) = p0;  \
            *reinterpret_cast<float4*>(&shh[(r0 + (rr)) * SW + 256 + 4 * l]) = p1; \
        }
        STAGE(0) STAGE(1) STAGE(2) STAGE(3)
#undef STAGE
    }
    __syncthreads();

    // ======== Phase 2: lane-local MFMA over 8 i's ========
    const int iw0 = i0 + w * 8;                         // this wave's first i
    const size_t orow = (size_t)(b0 + bi) * ROWL + dA;  // out lane base
    const size_t xrow = (size_t)(b0 + bi) * I_TOT;      // X/M lane base

    // prefetch iteration 0
    float4 phh = *reinterpret_cast<const float4*>(&shh[bi * SW + (w * 8) * 16 + dA]);
    float px = X[xrow + iw0];
    float pm = M[xrow + iw0];
    const float* Urp = U_r + iw0 * 256 + bi;
    const float* Uzp = U_z + iw0 * 256 + bi;
    const float* Uhp = U_h + iw0 * 256 + bi;
    float pur0 = Urp[(dA+0)*16], pur1 = Urp[(dA+1)*16],
          pur2 = Urp[(dA+2)*16], pur3 = Urp[(dA+3)*16];
    float puz0 = Uzp[(dA+0)*16], puz1 = Uzp[(dA+1)*16],
          puz2 = Uzp[(dA+2)*16], puz3 = Uzp[(dA+3)*16];
    float puh0 = Uhp[(dA+0)*16], puh1 = Uhp[(dA+1)*16],
          puh2 = Uhp[(dA+2)*16], puh3 = Uhp[(dA+3)*16];

    #pragma unroll
    for (int it = 0; it < 8; ++it) {
        const int i = iw0 + it;

        // ---- W/V/b for current i (feed the MFMA C-input) ----
        const float4 wr4 = *reinterpret_cast<const float4*>(W_r + i*16 + dA);
        const float4 wz4 = *reinterpret_cast<const float4*>(W_z + i*16 + dA);
        const float4 wh4 = *reinterpret_cast<const float4*>(W_h + i*16 + dA);
        const float4 vr4 = *reinterpret_cast<const float4*>(V_r + i*16 + dA);
        const float4 vz4 = *reinterpret_cast<const float4*>(V_z + i*16 + dA);
        const float4 vh4 = *reinterpret_cast<const float4*>(V_h + i*16 + dA);
        const float4 br4 = *reinterpret_cast<const float4*>(b_r + i*16 + dA);
        const float4 bz4 = *reinterpret_cast<const float4*>(b_z + i*16 + dA);
        const float4 bh4 = *reinterpret_cast<const float4*>(b_h + i*16 + dA);

        // ---- U fragments (hi-only, duplicated) ----
        bf16x8_t BUr = build_u(pur0, pur1, pur2, pur3);
        bf16x8_t BUz = build_u(puz0, puz1, puz2, puz3);
        bf16x8_t BUh = build_u(puh0, puh1, puh2, puh3);

        // ---- hh (staged h*gamma): lane owns hh[bi][dA..dA+3] ----
        float hh0 = phh.x, hh1 = phh.y, hh2 = phh.z, hh3 = phh.w;
        bf16x8_t Ahh = build_a(hh0, hh1, hh2, hh3);

        // ---- prefetch next iteration (skipped on last: static guard) ----
        float4 nhh; float nx, nm;
        float nur0, nur1, nur2, nur3, nuz0, nuz1, nuz2, nuz3, nuh0, nuh1, nuh2, nuh3;
        if (it < 7) {
            const int ipf = i + 1;
            nhh = *reinterpret_cast<const float4*>(
                &shh[bi * SW + (w * 8 + it + 1) * 16 + dA]);
            nx = X[xrow + ipf];
            nm = M[xrow + ipf];
            const float* nUr = U_r + ipf * 256 + bi;
            const float* nUz = U_z + ipf * 256 + bi;
            const float* nUh = U_h + ipf * 256 + bi;
            nur0 = nUr[(dA+0)*16]; nur1 = nUr[(dA+1)*16];
            nur2 = nUr[(dA+2)*16]; nur3 = nUr[(dA+3)*16];
            nuz0 = nUz[(dA+0)*16]; nuz1 = nUz[(dA+1)*16];
            nuz2 = nUz[(dA+2)*16]; nuz3 = nUz[(dA+3)*16];
            nuh0 = nUh[(dA+0)*16]; nuh1 = nUh[(dA+1)*16];
            nuh2 = nUh[(dA+2)*16]; nuh3 = nUh[(dA+3)*16];
        }

        // ---- r and z gates: one MFMA each, C = x*W + m*V + b ----
        f32x4_t initR, initZ, initH;
        initR[0] = fmaf(px, wr4.x, fmaf(pm, vr4.x, br4.x));
        initR[1] = fmaf(px, wr4.y, fmaf(pm, vr4.y, br4.y));
        initR[2] = fmaf(px, wr4.z, fmaf(pm, vr4.z, br4.z));
        initR[3] = fmaf(px, wr4.w, fmaf(pm, vr4.w, br4.w));
        initZ[0] = fmaf(px, wz4.x, fmaf(pm, vz4.x, bz4.x));
        initZ[1] = fmaf(px, wz4.y, fmaf(pm, vz4.y, bz4.y));
        initZ[2] = fmaf(px, wz4.z, fmaf(pm, vz4.z, bz4.z));
        initZ[3] = fmaf(px, wz4.w, fmaf(pm, vz4.w, bz4.w));
        f32x4_t accR = mm(BUr, Ahh, initR);
        f32x4_t accZ = mm(BUz, Ahh, initZ);

        // ---- rhh lane-local ----
        float rh0 = fast_sigmoid(accR[0]) * hh0;
        float rh1 = fast_sigmoid(accR[1]) * hh1;
        float rh2 = fast_sigmoid(accR[2]) * hh2;
        float rh3 = fast_sigmoid(accR[3]) * hh3;
        bf16x8_t Arh = build_a(rh0, rh1, rh2, rh3);

        // ---- h~ gate ----
        initH[0] = fmaf(px, wh4.x, fmaf(pm, vh4.x, bh4.x));
        initH[1] = fmaf(px, wh4.y, fmaf(pm, vh4.y, bh4.y));
        initH[2] = fmaf(px, wh4.z, fmaf(pm, vh4.z, bh4.z));
        initH[3] = fmaf(px, wh4.w, fmaf(pm, vh4.w, bh4.w));
        f32x4_t accH = mm(BUh, Arh, initH);

        // ---- out = z*hh + (1-z)*tanh(.), lane-local float4 store ----
        float4 o;
        {
            float z0 = fast_sigmoid(accZ[0]); float t0 = fast_tanh(accH[0]);
            o.x = fmaf(z0, hh0 - t0, t0);
            float z1 = fast_sigmoid(accZ[1]); float t1 = fast_tanh(accH[1]);
            o.y = fmaf(z1, hh1 - t1, t1);
            float z2 = fast_sigmoid(accZ[2]); float t2 = fast_tanh(accH[2]);
            o.z = fmaf(z2, hh2 - t2, t2);
            float z3 = fast_sigmoid(accZ[3]); float t3 = fast_tanh(accH[3]);
            o.w = fmaf(z3, hh3 - t3, t3);
        }
        *reinterpret_cast<float4*>(out + orow + (size_t)i * 16) = o;

        // ---- rotate prefetch ----
        if (it < 7) {
            phh = nhh; px = nx; pm = nm;
            pur0 = nur0; pur1 = nur1; pur2 = nur2; pur3 = nur3;
            puz0 = nuz0; puz1 = nuz1; puz2 = nuz2; puz3 = nuz3;
            puh0 = nuh0; puh1 = nuh1; puh2 = nuh2; puh3 = nuh3;
        }
    }
}

extern "C" void kernel_launch(void* const* d_in, const int* in_sizes, int n_in,
                              void* d_out, int out_size, void* d_ws, size_t ws_size,
                              hipStream_t stream) {
    const float* h       = (const float*)d_in[0];
    const float* X       = (const float*)d_in[1];
    const float* M       = (const float*)d_in[2];
    const float* gamma_h = (const float*)d_in[3];
    const float* W_r     = (const float*)d_in[4];
    const float* W_z     = (const float*)d_in[5];
    const float* W_h     = (const float*)d_in[6];
    const float* U_r     = (const float*)d_in[7];
    const float* U_z     = (const float*)d_in[8];
    const float* U_h     = (const float*)d_in[9];
    const float* V_r     = (const float*)d_in[10];
    const float* V_z     = (const float*)d_in[11];
    const float* V_h     = (const float*)d_in[12];
    const float* b_r     = (const float*)d_in[13];
    const float* b_z     = (const float*)d_in[14];
    const float* b_h     = (const float*)d_in[15];
    float* out = (float*)d_out;

    dim3 grid(I_TOT / 32, 16384 / 16);   // (4, 1024)
    dim3 block(256);
    gru_d_mfma<<<grid, block, 0, stream>>>(h, X, M, gamma_h,
                                           W_r, W_z, W_h,
                                           U_r, U_z, U_h,
                                           V_r, V_z, V_h,
                                           b_r, b_z, b_h,
                                           out);
}

// Round 15
// 112.958 us; speedup vs baseline: 1.2655x; 1.0113x over previous
//
#include <hip/hip_runtime.h>
#include <hip/hip_bf16.h>

// GRU-D cell: B=16384, I=128, D=16 -- staged-stream + lane-local MFMA.
// R15 = R14 with the occupancy lever: block i-tile halved 32->16 i's, LDS
// 33->16.6 KB => 9 blocks/CU (was 4), VGPR ~68 => up to 7 waves/SIMD
// (was 2.5 measured). R14 showed the kernel is latency-bound (all pipes
// <30%, ~10x stall factor); TLP is the direct multiplier on stall coverage.
// Phase 1: one contiguous 1-KB wave-load per row per array -> hh in LDS
// (16 x 256, stride 260 words: 2-way-bank pattern, free per m136).
// Phase 2: per wave 4 i's; 3 MFMAs/iter, hh-side hi/lo compensation,
// gate init as MFMA C-input, U prefetched one iteration ahead.

typedef float  f32x4_t  __attribute__((ext_vector_type(4)));
typedef short  bf16x8_t __attribute__((ext_vector_type(8)));

constexpr int I_TOT = 128;
constexpr int ROWL  = 2048;   // floats per batch row (I*D)
constexpr int SW    = 260;    // LDS row stride in words (256 + 4 pad)

__device__ __forceinline__ unsigned short bf16c(float x) {
    union { __hip_bfloat16 b; unsigned short u; } cv;
    cv.b = __float2bfloat16(x);
    return cv.u;
}
__device__ __forceinline__ float bf16_to_f(unsigned short b) {
    union { float f; unsigned u; } c; c.u = ((unsigned)b) << 16;
    return c.f;
}
__device__ __forceinline__ float fast_sigmoid(float x) {
    float e = __expf(-x);
    return __builtin_amdgcn_rcpf(1.0f + e);
}
__device__ __forceinline__ float fast_tanh(float x) {
    x = fminf(fmaxf(x, -10.0f), 10.0f);
    float e = __expf(-2.0f * x);
    return (1.0f - e) * __builtin_amdgcn_rcpf(1.0f + e);
}

// compensated A fragment: [hi(a0..a3) | lo(a0..a3)]
__device__ __forceinline__ bf16x8_t build_a(float a0, float a1, float a2, float a3) {
    unsigned short h0 = bf16c(a0), h1 = bf16c(a1),
                   h2 = bf16c(a2), h3 = bf16c(a3);
    unsigned short l0 = bf16c(a0 - bf16_to_f(h0));
    unsigned short l1 = bf16c(a1 - bf16_to_f(h1));
    unsigned short l2 = bf16c(a2 - bf16_to_f(h2));
    unsigned short l3 = bf16c(a3 - bf16_to_f(h3));
    bf16x8_t A;
    A[0] = (short)h0; A[1] = (short)h1; A[2] = (short)h2; A[3] = (short)h3;
    A[4] = (short)l0; A[5] = (short)l1; A[6] = (short)l2; A[7] = (short)l3;
    return A;
}

// U fragment, hi only, duplicated across both K halves
__device__ __forceinline__ bf16x8_t build_u(float u0, float u1, float u2, float u3) {
    unsigned short h0 = bf16c(u0), h1 = bf16c(u1),
                   h2 = bf16c(u2), h3 = bf16c(u3);
    bf16x8_t B;
    B[0] = (short)h0; B[1] = (short)h1; B[2] = (short)h2; B[3] = (short)h3;
    B[4] = (short)h0; B[5] = (short)h1; B[6] = (short)h2; B[7] = (short)h3;
    return B;
}

__device__ __forceinline__ f32x4_t mm(bf16x8_t a, bf16x8_t b, f32x4_t c) {
    return __builtin_amdgcn_mfma_f32_16x16x32_bf16(a, b, c, 0, 0, 0);
}

__global__ __launch_bounds__(256)
__attribute__((amdgpu_waves_per_eu(4, 8)))
void gru_d_mfma(
    const float* __restrict__ h,
    const float* __restrict__ X,
    const float* __restrict__ M,
    const float* __restrict__ gam,
    const float* __restrict__ W_r, const float* __restrict__ W_z, const float* __restrict__ W_h,
    const float* __restrict__ U_r, const float* __restrict__ U_z, const float* __restrict__ U_h,
    const float* __restrict__ V_r, const float* __restrict__ V_z, const float* __restrict__ V_h,
    const float* __restrict__ b_r, const float* __restrict__ b_z, const float* __restrict__ b_h,
    float* __restrict__ out)
{
    __shared__ __align__(16) float shh[16 * SW];

    const int t  = threadIdx.x;
    const int w  = t >> 6;              // wave in block
    const int l  = t & 63;              // lane
    const int bi = l & 15;              // batch row within tile (phase 2)
    const int dA = (l >> 4) * 4;        // d-slot / out-col base (phase 2)

    const int b0 = blockIdx.y * 16;     // b-tile
    const int i0 = blockIdx.x * 16;     // block's first feature (16-i tile)

    // ======== Phase 1: contiguous stream -> hh in LDS ========
    // Wave w stages rows 4w..4w+3; one contiguous 1-KB wave load per array.
    {
        const int r0 = 4 * w;
#define STAGE(rr)                                                             \
        {                                                                     \
            const size_t gb = (size_t)(b0 + r0 + (rr)) * ROWL + i0 * 16;      \
            float4 hv = *reinterpret_cast<const float4*>(h   + gb + 4 * l);   \
            float4 gv = *reinterpret_cast<const float4*>(gam + gb + 4 * l);   \
            float4 p;                                                         \
            p.x = hv.x * gv.x; p.y = hv.y * gv.y;                             \
            p.z = hv.z * gv.z; p.w = hv.w * gv.w;                             \
            *reinterpret_cast<float4*>(&shh[(r0 + (rr)) * SW + 4 * l]) = p;   \
        }
        STAGE(0) STAGE(1) STAGE(2) STAGE(3)
#undef STAGE
    }
    __syncthreads();

    // ======== Phase 2: lane-local MFMA over 4 i's ========
    const int iw0 = i0 + w * 4;                         // this wave's first i
    const size_t orow = (size_t)(b0 + bi) * ROWL + dA;  // out lane base
    const size_t xrow = (size_t)(b0 + bi) * I_TOT;      // X/M lane base

    // prefetch iteration 0
    float4 phh = *reinterpret_cast<const float4*>(&shh[bi * SW + (w * 4) * 16 + dA]);
    float px = X[xrow + iw0];
    float pm = M[xrow + iw0];
    const float* Urp = U_r + iw0 * 256 + bi;
    const float* Uzp = U_z + iw0 * 256 + bi;
    const float* Uhp = U_h + iw0 * 256 + bi;
    float pur0 = Urp[(dA+0)*16], pur1 = Urp[(dA+1)*16],
          pur2 = Urp[(dA+2)*16], pur3 = Urp[(dA+3)*16];
    float puz0 = Uzp[(dA+0)*16], puz1 = Uzp[(dA+1)*16],
          puz2 = Uzp[(dA+2)*16], puz3 = Uzp[(dA+3)*16];
    float puh0 = Uhp[(dA+0)*16], puh1 = Uhp[(dA+1)*16],
          puh2 = Uhp[(dA+2)*16], puh3 = Uhp[(dA+3)*16];

    #pragma unroll
    for (int it = 0; it < 4; ++it) {
        const int i = iw0 + it;

        // ---- W/V/b for current i (feed the MFMA C-input) ----
        const float4 wr4 = *reinterpret_cast<const float4*>(W_r + i*16 + dA);
        const float4 wz4 = *reinterpret_cast<const float4*>(W_z + i*16 + dA);
        const float4 wh4 = *reinterpret_cast<const float4*>(W_h + i*16 + dA);
        const float4 vr4 = *reinterpret_cast<const float4*>(V_r + i*16 + dA);
        const float4 vz4 = *reinterpret_cast<const float4*>(V_z + i*16 + dA);
        const float4 vh4 = *reinterpret_cast<const float4*>(V_h + i*16 + dA);
        const float4 br4 = *reinterpret_cast<const float4*>(b_r + i*16 + dA);
        const float4 bz4 = *reinterpret_cast<const float4*>(b_z + i*16 + dA);
        const float4 bh4 = *reinterpret_cast<const float4*>(b_h + i*16 + dA);

        // ---- U fragments (hi-only, duplicated) ----
        bf16x8_t BUr = build_u(pur0, pur1, pur2, pur3);
        bf16x8_t BUz = build_u(puz0, puz1, puz2, puz3);
        bf16x8_t BUh = build_u(puh0, puh1, puh2, puh3);

        // ---- hh (staged h*gamma): lane owns hh[bi][dA..dA+3] ----
        float hh0 = phh.x, hh1 = phh.y, hh2 = phh.z, hh3 = phh.w;
        bf16x8_t Ahh = build_a(hh0, hh1, hh2, hh3);

        // ---- prefetch next iteration (static guard, loop fully unrolled) ----
        float4 nhh; float nx, nm;
        float nur0, nur1, nur2, nur3, nuz0, nuz1, nuz2, nuz3, nuh0, nuh1, nuh2, nuh3;
        if (it < 3) {
            const int ipf = i + 1;
            nhh = *reinterpret_cast<const float4*>(
                &shh[bi * SW + (w * 4 + it + 1) * 16 + dA]);
            nx = X[xrow + ipf];
            nm = M[xrow + ipf];
            const float* nUr = U_r + ipf * 256 + bi;
            const float* nUz = U_z + ipf * 256 + bi;
            const float* nUh = U_h + ipf * 256 + bi;
            nur0 = nUr[(dA+0)*16]; nur1 = nUr[(dA+1)*16];
            nur2 = nUr[(dA+2)*16]; nur3 = nUr[(dA+3)*16];
            nuz0 = nUz[(dA+0)*16]; nuz1 = nUz[(dA+1)*16];
            nuz2 = nUz[(dA+2)*16]; nuz3 = nUz[(dA+3)*16];
            nuh0 = nUh[(dA+0)*16]; nuh1 = nUh[(dA+1)*16];
            nuh2 = nUh[(dA+2)*16]; nuh3 = nUh[(dA+3)*16];
        }

        // ---- r and z gates: one MFMA each, C = x*W + m*V + b ----
        f32x4_t initR, initZ, initH;
        initR[0] = fmaf(px, wr4.x, fmaf(pm, vr4.x, br4.x));
        initR[1] = fmaf(px, wr4.y, fmaf(pm, vr4.y, br4.y));
        initR[2] = fmaf(px, wr4.z, fmaf(pm, vr4.z, br4.z));
        initR[3] = fmaf(px, wr4.w, fmaf(pm, vr4.w, br4.w));
        initZ[0] = fmaf(px, wz4.x, fmaf(pm, vz4.x, bz4.x));
        initZ[1] = fmaf(px, wz4.y, fmaf(pm, vz4.y, bz4.y));
        initZ[2] = fmaf(px, wz4.z, fmaf(pm, vz4.z, bz4.z));
        initZ[3] = fmaf(px, wz4.w, fmaf(pm, vz4.w, bz4.w));
        f32x4_t accR = mm(BUr, Ahh, initR);
        f32x4_t accZ = mm(BUz, Ahh, initZ);

        // ---- rhh lane-local ----
        float rh0 = fast_sigmoid(accR[0]) * hh0;
        float rh1 = fast_sigmoid(accR[1]) * hh1;
        float rh2 = fast_sigmoid(accR[2]) * hh2;
        float rh3 = fast_sigmoid(accR[3]) * hh3;
        bf16x8_t Arh = build_a(rh0, rh1, rh2, rh3);

        // ---- h~ gate ----
        initH[0] = fmaf(px, wh4.x, fmaf(pm, vh4.x, bh4.x));
        initH[1] = fmaf(px, wh4.y, fmaf(pm, vh4.y, bh4.y));
        initH[2] = fmaf(px, wh4.z, fmaf(pm, vh4.z, bh4.z));
        initH[3] = fmaf(px, wh4.w, fmaf(pm, vh4.w, bh4.w));
        f32x4_t accH = mm(BUh, Arh, initH);

        // ---- out = z*hh + (1-z)*tanh(.), lane-local float4 store ----
        float4 o;
        {
            float z0 = fast_sigmoid(accZ[0]); float t0 = fast_tanh(accH[0]);
            o.x = fmaf(z0, hh0 - t0, t0);
            float z1 = fast_sigmoid(accZ[1]); float t1 = fast_tanh(accH[1]);
            o.y = fmaf(z1, hh1 - t1, t1);
            float z2 = fast_sigmoid(accZ[2]); float t2 = fast_tanh(accH[2]);
            o.z = fmaf(z2, hh2 - t2, t2);
            float z3 = fast_sigmoid(accZ[3]); float t3 = fast_tanh(accH[3]);
            o.w = fmaf(z3, hh3 - t3, t3);
        }
        *reinterpret_cast<float4*>(out + orow + (size_t)i * 16) = o;

        // ---- rotate prefetch ----
        if (it < 3) {
            phh = nhh; px = nx; pm = nm;
            pur0 = nur0; pur1 = nur1; pur2 = nur2; pur3 = nur3;
            puz0 = nuz0; puz1 = nuz1; puz2 = nuz2; puz3 = nuz3;
            puh0 = nuh0; puh1 = nuh1; puh2 = nuh2; puh3 = nuh3;
        }
    }
}

extern "C" void kernel_launch(void* const* d_in, const int* in_sizes, int n_in,
                              void* d_out, int out_size, void* d_ws, size_t ws_size,
                              hipStream_t stream) {
    const float* h       = (const float*)d_in[0];
    const float* X       = (const float*)d_in[1];
    const float* M       = (const float*)d_in[2];
    const float* gamma_h = (const float*)d_in[3];
    const float* W_r     = (const float*)d_in[4];
    const float* W_z     = (const float*)d_in[5];
    const float* W_h     = (const float*)d_in[6];
    const float* U_r     = (const float*)d_in[7];
    const float* U_z     = (const float*)d_in[8];
    const float* U_h     = (const float*)d_in[9];
    const float* V_r     = (const float*)d_in[10];
    const float* V_z     = (const float*)d_in[11];
    const float* V_h     = (const float*)d_in[12];
    const float* b_r     = (const float*)d_in[13];
    const float* b_z     = (const float*)d_in[14];
    const float* b_h     = (const float*)d_in[15];
    float* out = (float*)d_out;

    dim3 grid(I_TOT / 16, 16384 / 16);   // (8, 1024) = 8192 blocks
    dim3 block(256);
    gru_d_mfma<<<grid, block, 0, stream>>>(h, X, M, gamma_h,
                                           W_r, W_z, W_h,
                                           U_r, U_z, U_h,
                                           V_r, V_z, V_h,
                                           b_r, b_z, b_h,
                                           out);
}

// Round 16
// 108.008 us; speedup vs baseline: 1.3235x; 1.0458x over previous
//
#include <hip/hip_runtime.h>
#include <hip/hip_bf16.h>

// GRU-D cell: B=16384, I=128, D=16 -- fully-staged streams + lane-local MFMA.
// R16 = R15 + contiguous STORE path. R15 showed TLP is not the binder
// (occupancy 31->50% with zero dur change): the ~2.1 TB/s wall is the
// memory pattern. The one remaining scattered bulk stream was the store
// (16 x 64-B granules per wave-store). Now phase 2 writes gate outputs into
// the SAME LDS tile (in-place: each (row,col) is read-then-written by the
// same lane in program order -> no hazard), and phase 3 streams the tile out
// with contiguous 1-KB wave-stores -- the mirror of phase 1's loads. All
// bulk global traffic (h, gamma, out) is memcpy-shaped; only L2-resident
// U/W/V/X/M gathers remain.

typedef float  f32x4_t  __attribute__((ext_vector_type(4)));
typedef short  bf16x8_t __attribute__((ext_vector_type(8)));

constexpr int I_TOT = 128;
constexpr int ROWL  = 2048;   // floats per batch row (I*D)
constexpr int SW    = 260;    // LDS row stride in words (256 + 4 pad)

__device__ __forceinline__ unsigned short bf16c(float x) {
    union { __hip_bfloat16 b; unsigned short u; } cv;
    cv.b = __float2bfloat16(x);
    return cv.u;
}
__device__ __forceinline__ float bf16_to_f(unsigned short b) {
    union { float f; unsigned u; } c; c.u = ((unsigned)b) << 16;
    return c.f;
}
__device__ __forceinline__ float fast_sigmoid(float x) {
    float e = __expf(-x);
    return __builtin_amdgcn_rcpf(1.0f + e);
}
__device__ __forceinline__ float fast_tanh(float x) {
    x = fminf(fmaxf(x, -10.0f), 10.0f);
    float e = __expf(-2.0f * x);
    return (1.0f - e) * __builtin_amdgcn_rcpf(1.0f + e);
}

// compensated A fragment: [hi(a0..a3) | lo(a0..a3)]
__device__ __forceinline__ bf16x8_t build_a(float a0, float a1, float a2, float a3) {
    unsigned short h0 = bf16c(a0), h1 = bf16c(a1),
                   h2 = bf16c(a2), h3 = bf16c(a3);
    unsigned short l0 = bf16c(a0 - bf16_to_f(h0));
    unsigned short l1 = bf16c(a1 - bf16_to_f(h1));
    unsigned short l2 = bf16c(a2 - bf16_to_f(h2));
    unsigned short l3 = bf16c(a3 - bf16_to_f(h3));
    bf16x8_t A;
    A[0] = (short)h0; A[1] = (short)h1; A[2] = (short)h2; A[3] = (short)h3;
    A[4] = (short)l0; A[5] = (short)l1; A[6] = (short)l2; A[7] = (short)l3;
    return A;
}

// U fragment, hi only, duplicated across both K halves
__device__ __forceinline__ bf16x8_t build_u(float u0, float u1, float u2, float u3) {
    unsigned short h0 = bf16c(u0), h1 = bf16c(u1),
                   h2 = bf16c(u2), h3 = bf16c(u3);
    bf16x8_t B;
    B[0] = (short)h0; B[1] = (short)h1; B[2] = (short)h2; B[3] = (short)h3;
    B[4] = (short)h0; B[5] = (short)h1; B[6] = (short)h2; B[7] = (short)h3;
    return B;
}

__device__ __forceinline__ f32x4_t mm(bf16x8_t a, bf16x8_t b, f32x4_t c) {
    return __builtin_amdgcn_mfma_f32_16x16x32_bf16(a, b, c, 0, 0, 0);
}

__global__ __launch_bounds__(256)
__attribute__((amdgpu_waves_per_eu(4, 8)))
void gru_d_mfma(
    const float* __restrict__ h,
    const float* __restrict__ X,
    const float* __restrict__ M,
    const float* __restrict__ gam,
    const float* __restrict__ W_r, const float* __restrict__ W_z, const float* __restrict__ W_h,
    const float* __restrict__ U_r, const float* __restrict__ U_z, const float* __restrict__ U_h,
    const float* __restrict__ V_r, const float* __restrict__ V_z, const float* __restrict__ V_h,
    const float* __restrict__ b_r, const float* __restrict__ b_z, const float* __restrict__ b_h,
    float* __restrict__ out)
{
    __shared__ __align__(16) float shh[16 * SW];

    const int t  = threadIdx.x;
    const int w  = t >> 6;              // wave in block
    const int l  = t & 63;              // lane
    const int bi = l & 15;              // batch row within tile (phase 2)
    const int dA = (l >> 4) * 4;        // d-slot / out-col base (phase 2)

    const int b0 = blockIdx.y * 16;     // b-tile
    const int i0 = blockIdx.x * 16;     // block's first feature (16-i tile)

    // ======== Phase 1: contiguous stream -> hh in LDS ========
    {
        const int r0 = 4 * w;
#define STAGE(rr)                                                             \
        {                                                                     \
            const size_t gb = (size_t)(b0 + r0 + (rr)) * ROWL + i0 * 16;      \
            float4 hv = *reinterpret_cast<const float4*>(h   + gb + 4 * l);   \
            float4 gv = *reinterpret_cast<const float4*>(gam + gb + 4 * l);   \
            float4 p;                                                         \
            p.x = hv.x * gv.x; p.y = hv.y * gv.y;                             \
            p.z = hv.z * gv.z; p.w = hv.w * gv.w;                             \
            *reinterpret_cast<float4*>(&shh[(r0 + (rr)) * SW + 4 * l]) = p;   \
        }
        STAGE(0) STAGE(1) STAGE(2) STAGE(3)
#undef STAGE
    }
    __syncthreads();

    // ======== Phase 2: lane-local MFMA over 4 i's; out -> LDS in place ====
    const int iw0 = i0 + w * 4;                         // this wave's first i
    const size_t xrow = (size_t)(b0 + bi) * I_TOT;      // X/M lane base

    // prefetch iteration 0
    float4 phh = *reinterpret_cast<const float4*>(&shh[bi * SW + (w * 4) * 16 + dA]);
    float px = X[xrow + iw0];
    float pm = M[xrow + iw0];
    const float* Urp = U_r + iw0 * 256 + bi;
    const float* Uzp = U_z + iw0 * 256 + bi;
    const float* Uhp = U_h + iw0 * 256 + bi;
    float pur0 = Urp[(dA+0)*16], pur1 = Urp[(dA+1)*16],
          pur2 = Urp[(dA+2)*16], pur3 = Urp[(dA+3)*16];
    float puz0 = Uzp[(dA+0)*16], puz1 = Uzp[(dA+1)*16],
          puz2 = Uzp[(dA+2)*16], puz3 = Uzp[(dA+3)*16];
    float puh0 = Uhp[(dA+0)*16], puh1 = Uhp[(dA+1)*16],
          puh2 = Uhp[(dA+2)*16], puh3 = Uhp[(dA+3)*16];

    #pragma unroll
    for (int it = 0; it < 4; ++it) {
        const int i = iw0 + it;

        // ---- W/V/b for current i (feed the MFMA C-input) ----
        const float4 wr4 = *reinterpret_cast<const float4*>(W_r + i*16 + dA);
        const float4 wz4 = *reinterpret_cast<const float4*>(W_z + i*16 + dA);
        const float4 wh4 = *reinterpret_cast<const float4*>(W_h + i*16 + dA);
        const float4 vr4 = *reinterpret_cast<const float4*>(V_r + i*16 + dA);
        const float4 vz4 = *reinterpret_cast<const float4*>(V_z + i*16 + dA);
        const float4 vh4 = *reinterpret_cast<const float4*>(V_h + i*16 + dA);
        const float4 br4 = *reinterpret_cast<const float4*>(b_r + i*16 + dA);
        const float4 bz4 = *reinterpret_cast<const float4*>(b_z + i*16 + dA);
        const float4 bh4 = *reinterpret_cast<const float4*>(b_h + i*16 + dA);

        // ---- U fragments (hi-only, duplicated) ----
        bf16x8_t BUr = build_u(pur0, pur1, pur2, pur3);
        bf16x8_t BUz = build_u(puz0, puz1, puz2, puz3);
        bf16x8_t BUh = build_u(puh0, puh1, puh2, puh3);

        // ---- hh (staged h*gamma): lane owns hh[bi][dA..dA+3] ----
        float hh0 = phh.x, hh1 = phh.y, hh2 = phh.z, hh3 = phh.w;
        bf16x8_t Ahh = build_a(hh0, hh1, hh2, hh3);

        // ---- prefetch next iteration (static guard, loop fully unrolled) ----
        float4 nhh; float nx, nm;
        float nur0, nur1, nur2, nur3, nuz0, nuz1, nuz2, nuz3, nuh0, nuh1, nuh2, nuh3;
        if (it < 3) {
            const int ipf = i + 1;
            nhh = *reinterpret_cast<const float4*>(
                &shh[bi * SW + (w * 4 + it + 1) * 16 + dA]);
            nx = X[xrow + ipf];
            nm = M[xrow + ipf];
            const float* nUr = U_r + ipf * 256 + bi;
            const float* nUz = U_z + ipf * 256 + bi;
            const float* nUh = U_h + ipf * 256 + bi;
            nur0 = nUr[(dA+0)*16]; nur1 = nUr[(dA+1)*16];
            nur2 = nUr[(dA+2)*16]; nur3 = nUr[(dA+3)*16];
            nuz0 = nUz[(dA+0)*16]; nuz1 = nUz[(dA+1)*16];
            nuz2 = nUz[(dA+2)*16]; nuz3 = nUz[(dA+3)*16];
            nuh0 = nUh[(dA+0)*16]; nuh1 = nUh[(dA+1)*16];
            nuh2 = nUh[(dA+2)*16]; nuh3 = nUh[(dA+3)*16];
        }

        // ---- r and z gates: one MFMA each, C = x*W + m*V + b ----
        f32x4_t initR, initZ, initH;
        initR[0] = fmaf(px, wr4.x, fmaf(pm, vr4.x, br4.x));
        initR[1] = fmaf(px, wr4.y, fmaf(pm, vr4.y, br4.y));
        initR[2] = fmaf(px, wr4.z, fmaf(pm, vr4.z, br4.z));
        initR[3] = fmaf(px, wr4.w, fmaf(pm, vr4.w, br4.w));
        initZ[0] = fmaf(px, wz4.x, fmaf(pm, vz4.x, bz4.x));
        initZ[1] = fmaf(px, wz4.y, fmaf(pm, vz4.y, bz4.y));
        initZ[2] = fmaf(px, wz4.z, fmaf(pm, vz4.z, bz4.z));
        initZ[3] = fmaf(px, wz4.w, fmaf(pm, vz4.w, bz4.w));
        f32x4_t accR = mm(BUr, Ahh, initR);
        f32x4_t accZ = mm(BUz, Ahh, initZ);

        // ---- rhh lane-local ----
        float rh0 = fast_sigmoid(accR[0]) * hh0;
        float rh1 = fast_sigmoid(accR[1]) * hh1;
        float rh2 = fast_sigmoid(accR[2]) * hh2;
        float rh3 = fast_sigmoid(accR[3]) * hh3;
        bf16x8_t Arh = build_a(rh0, rh1, rh2, rh3);

        // ---- h~ gate ----
        initH[0] = fmaf(px, wh4.x, fmaf(pm, vh4.x, bh4.x));
        initH[1] = fmaf(px, wh4.y, fmaf(pm, vh4.y, bh4.y));
        initH[2] = fmaf(px, wh4.z, fmaf(pm, vh4.z, bh4.z));
        initH[3] = fmaf(px, wh4.w, fmaf(pm, vh4.w, bh4.w));
        f32x4_t accH = mm(BUh, Arh, initH);

        // ---- out = z*hh + (1-z)*tanh(.), written IN PLACE to LDS ----
        // Same lane read this exact location as hh (prefetch of iter it) --
        // read-then-write in program order, no cross-lane hazard.
        float4 o;
        {
            float z0 = fast_sigmoid(accZ[0]); float t0 = fast_tanh(accH[0]);
            o.x = fmaf(z0, hh0 - t0, t0);
            float z1 = fast_sigmoid(accZ[1]); float t1 = fast_tanh(accH[1]);
            o.y = fmaf(z1, hh1 - t1, t1);
            float z2 = fast_sigmoid(accZ[2]); float t2 = fast_tanh(accH[2]);
            o.z = fmaf(z2, hh2 - t2, t2);
            float z3 = fast_sigmoid(accZ[3]); float t3 = fast_tanh(accH[3]);
            o.w = fmaf(z3, hh3 - t3, t3);
        }
        *reinterpret_cast<float4*>(&shh[bi * SW + (w * 4 + it) * 16 + dA]) = o;

        // ---- rotate prefetch ----
        if (it < 3) {
            phh = nhh; px = nx; pm = nm;
            pur0 = nur0; pur1 = nur1; pur2 = nur2; pur3 = nur3;
            puz0 = nuz0; puz1 = nuz1; puz2 = nuz2; puz3 = nuz3;
            puh0 = nuh0; puh1 = nuh1; puh2 = nuh2; puh3 = nuh3;
        }
    }
    __syncthreads();

    // ======== Phase 3: contiguous stream LDS -> out (mirror of phase 1) ====
    {
        const int r0 = 4 * w;
#define UNSTAGE(rr)                                                           \
        {                                                                     \
            const size_t gb = (size_t)(b0 + r0 + (rr)) * ROWL + i0 * 16;      \
            float4 v = *reinterpret_cast<const float4*>(                      \
                &shh[(r0 + (rr)) * SW + 4 * l]);                              \
            *reinterpret_cast<float4*>(out + gb + 4 * l) = v;                 \
        }
        UNSTAGE(0) UNSTAGE(1) UNSTAGE(2) UNSTAGE(3)
#undef UNSTAGE
    }
}

extern "C" void kernel_launch(void* const* d_in, const int* in_sizes, int n_in,
                              void* d_out, int out_size, void* d_ws, size_t ws_size,
                              hipStream_t stream) {
    const float* h       = (const float*)d_in[0];
    const float* X       = (const float*)d_in[1];
    const float* M       = (const float*)d_in[2];
    const float* gamma_h = (const float*)d_in[3];
    const float* W_r     = (const float*)d_in[4];
    const float* W_z     = (const float*)d_in[5];
    const float* W_h     = (const float*)d_in[6];
    const float* U_r     = (const float*)d_in[7];
    const float* U_z     = (const float*)d_in[8];
    const float* U_h     = (const float*)d_in[9];
    const float* V_r     = (const float*)d_in[10];
    const float* V_z     = (const float*)d_in[11];
    const float* V_h     = (const float*)d_in[12];
    const float* b_r     = (const float*)d_in[13];
    const float* b_z     = (const float*)d_in[14];
    const float* b_h     = (const float*)d_in[15];
    float* out = (float*)d_out;

    dim3 grid(I_TOT / 16, 16384 / 16);   // (8, 1024) = 8192 blocks
    dim3 block(256);
    gru_d_mfma<<<grid, block, 0, stream>>>(h, X, M, gamma_h,
                                           W_r, W_z, W_h,
                                           U_r, U_z, U_h,
                                           V_r, V_z, V_h,
                                           b_r, b_z, b_h,
                                           out);
}